// Round 1
// baseline (18355.859 us; speedup 1.0000x reference)
//
#include <hip/hip_runtime.h>
#include <stddef.h>

// CFRMClassifier: tokens->emb->GRU(T=1024,H=512,B=64)->EMA summaries->classifier
// Round 1: correctness-first full pipeline.
//   - xp = emb[tok] @ w_ih^T + b_ih  via bf16 MFMA GEMM (stored bf16)
//   - GRU scan: 64 WGs (one per batch elem), streamed bf16 packed-transposed w_hh
//   - tail kernels build flatT[k][b] then classify.
// Workspace need: ~392 MB.

typedef unsigned short u16;
typedef short s8v __attribute__((ext_vector_type(8)));
typedef float f4v __attribute__((ext_vector_type(4)));

#define B_ 64
#define T_ 1024
#define H_ 512
#define G_ 1536       // 3H
#define C_ 32
#define M_ 65536      // B*T
#define NCLS_ 1000
#define KCLS_ 16448   // C*(H+2)

__device__ __forceinline__ u16 f2bf(float f) {
    unsigned u = __float_as_uint(f);
    unsigned r = (u + 0x7fffu + ((u >> 16) & 1u)) >> 16;
    return (u16)r;
}
__device__ __forceinline__ float b2f(u16 x) { return __uint_as_float(((unsigned)x) << 16); }
__device__ __forceinline__ float bflo(unsigned u) { return __uint_as_float(u << 16); }
__device__ __forceinline__ float bfhi(unsigned u) { return __uint_as_float(u & 0xffff0000u); }
__device__ __forceinline__ float sigmoidf_(float x) { return 1.0f / (1.0f + __expf(-x)); }
__device__ __forceinline__ float tanhf_(float x) { return 1.0f - 2.0f / (1.0f + __expf(2.0f * x)); }

// ---------- prep kernels ----------
__global__ void k_cast_wih(const float* __restrict__ src, u16* __restrict__ dst) {
    int i = blockIdx.x * 256 + threadIdx.x;
    if (i < G_ * H_) dst[i] = f2bf(src[i]);
}

// wP[k2*1536 + g] = pack(w_hh[g][2k2], w_hh[g][2k2+1])
__global__ void k_pack_whh(const float* __restrict__ w_hh, unsigned* __restrict__ wP) {
    int idx = blockIdx.x * 256 + threadIdx.x;
    if (idx >= 256 * G_) return;
    int k2 = idx / G_, g = idx % G_;
    float lo = w_hh[g * H_ + 2 * k2];
    float hi = w_hh[g * H_ + 2 * k2 + 1];
    wP[idx] = (unsigned)f2bf(lo) | ((unsigned)f2bf(hi) << 16);
}

__global__ void k_decay(float* __restrict__ decay) {
    int t = blockIdx.x * 256 + threadIdx.x;
    if (t < T_) decay[t] = powf(0.85f, (float)(T_ - 1 - t));
}

// ---------- embedding gather + bf16 cast ----------
__global__ __launch_bounds__(256) void k_embed(const int* __restrict__ tokens,
                                               const float* __restrict__ emb,
                                               u16* __restrict__ X) {
    int g = blockIdx.x * 256 + threadIdx.x;  // 4,194,304 total = 65536 rows * 64 chunks
    int m = g >> 6, c8 = g & 63;
    int tok = tokens[m];
    const float4* src = (const float4*)(emb + (size_t)tok * H_ + c8 * 8);
    float4 f0 = src[0], f1 = src[1];
    uint4 pk;
    pk.x = (unsigned)f2bf(f0.x) | ((unsigned)f2bf(f0.y) << 16);
    pk.y = (unsigned)f2bf(f0.z) | ((unsigned)f2bf(f0.w) << 16);
    pk.z = (unsigned)f2bf(f1.x) | ((unsigned)f2bf(f1.y) << 16);
    pk.w = (unsigned)f2bf(f1.z) | ((unsigned)f2bf(f1.w) << 16);
    *(uint4*)(X + (size_t)m * H_ + c8 * 8) = pk;
}

// ---------- xp GEMM: xp[m][g] = sum_k X[m][k]*Wih[g][k] + b_ih[g], stored bf16 ----------
// block: 256 thr = 4 waves; tile M=64 (wave=16 rows), N=128; K staged in 32-chunks (B in LDS)
__global__ __launch_bounds__(256) void k_xp(const u16* __restrict__ X,
                                            const u16* __restrict__ Wih,
                                            const float* __restrict__ b_ih,
                                            u16* __restrict__ xp) {
    __shared__ u16 Bs[128 * 48];  // row stride 48 elems (96B): 16B-aligned, 4-way bank worst
    int tid = threadIdx.x;
    int bid = blockIdx.x;
    int m0 = (bid / 12) * 64;
    int n0 = (bid % 12) * 128;
    int w = tid >> 6, lane = tid & 63;
    int lm = lane & 15, q = lane >> 4;
    f4v acc[8];
#pragma unroll
    for (int i = 0; i < 8; i++) acc[i] = (f4v){0.f, 0.f, 0.f, 0.f};
    int arow = m0 + w * 16 + lm;
    const u16* Aptr = X + (size_t)arow * H_ + q * 8;

    int srow = tid >> 1, shalf = tid & 1;
    for (int kk = 0; kk < H_; kk += 32) {
        const uint4* src = (const uint4*)(Wih + (size_t)(n0 + srow) * H_ + kk + shalf * 16);
        uint4 v0 = src[0], v1 = src[1];
        uint4* dst = (uint4*)(Bs + srow * 48 + shalf * 16);
        dst[0] = v0; dst[1] = v1;
        __syncthreads();
        s8v a = *(const s8v*)(Aptr + kk);
#pragma unroll
        for (int nt = 0; nt < 8; nt++) {
            s8v bf = *(const s8v*)(Bs + (nt * 16 + lm) * 48 + q * 8);
            acc[nt] = __builtin_amdgcn_mfma_f32_16x16x32_bf16(a, bf, acc[nt], 0, 0, 0);
        }
        __syncthreads();
    }
#pragma unroll
    for (int nt = 0; nt < 8; nt++) {
        int col = n0 + nt * 16 + lm;
        float bias = b_ih[col];
#pragma unroll
        for (int r = 0; r < 4; r++) {
            int row = m0 + w * 16 + q * 4 + r;
            xp[(size_t)row * G_ + col] = f2bf(acc[nt][r] + bias);
        }
    }
}

// ---------- GRU scan: 64 blocks (one per b) x 512 threads (one per hidden j) ----------
__global__ __launch_bounds__(512) void k_scan(const unsigned* __restrict__ wP,
                                              const u16* __restrict__ xp,
                                              const float* __restrict__ b_hh,
                                              float* __restrict__ hseq) {
    int b = blockIdx.x, j = threadIdx.x;
    __shared__ float hsh[512];
    hsh[j] = 0.f;
    float hprev = 0.f;
    float bhr = b_hh[j], bhz = b_hh[H_ + j], bhn = b_hh[2 * H_ + j];
    const u16* xpb = xp + (size_t)b * T_ * G_;
    __syncthreads();
    for (int t = 0; t < T_; t++) {
        float ar = 0.f, az = 0.f, an = 0.f;
        const float2* h2 = (const float2*)hsh;
#pragma unroll 4
        for (int k2 = 0; k2 < 256; k2++) {
            unsigned wr = wP[k2 * G_ + j];
            unsigned wz = wP[k2 * G_ + H_ + j];
            unsigned wn = wP[k2 * G_ + 2 * H_ + j];
            float2 hk = h2[k2];
            ar = fmaf(bflo(wr), hk.x, ar); ar = fmaf(bfhi(wr), hk.y, ar);
            az = fmaf(bflo(wz), hk.x, az); az = fmaf(bfhi(wz), hk.y, az);
            an = fmaf(bflo(wn), hk.x, an); an = fmaf(bfhi(wn), hk.y, an);
        }
        float xr = b2f(xpb[(size_t)t * G_ + j]);
        float xz = b2f(xpb[(size_t)t * G_ + H_ + j]);
        float xn = b2f(xpb[(size_t)t * G_ + 2 * H_ + j]);
        float r = sigmoidf_(xr + ar + bhr);
        float z = sigmoidf_(xz + az + bhz);
        float n = tanhf_(xn + r * (an + bhn));
        float hn = (1.f - z) * n + z * hprev;
        __syncthreads();
        hsh[j] = hn;
        hprev = hn;
        hseq[((size_t)t * B_ + b) * H_ + j] = hn;
        __syncthreads();
    }
}

// ---------- decay-weighted & plain sums of h_seq (transposed outputs [h][b]) ----------
__global__ __launch_bounds__(512) void k_hw(const float* __restrict__ hseq,
                                            const float* __restrict__ decay,
                                            float* __restrict__ hwT,
                                            float* __restrict__ hsumT) {
    int b = blockIdx.x, h = threadIdx.x;
    float aw = 0.f, as = 0.f;
    for (int t = 0; t < T_; t++) {
        float v = hseq[((size_t)t * B_ + b) * H_ + h];
        aw = fmaf(decay[t], v, aw);
        as += v;
    }
    hwT[h * B_ + b] = aw;
    hsumT[h * B_ + b] = as;
}

// ---------- spreads: sigmoid projections accumulated with decay ----------
__global__ __launch_bounds__(512) void k_sd(const float* __restrict__ hseq,
                                            const float* __restrict__ ws,
                                            const float* __restrict__ bs,
                                            const float* __restrict__ decay,
                                            float* __restrict__ flatT) {
    int b = blockIdx.x, tid = threadIdx.x;
    __shared__ float hl[512];
    int c = tid >> 4, p = tid & 15;
    float wreg[32];
#pragma unroll
    for (int i = 0; i < 32; i++) wreg[i] = ws[c * H_ + p + 16 * i];
    float bsc = bs[c];
    float acc = 0.f;
    for (int t = 0; t < T_; t++) {
        __syncthreads();
        hl[tid] = hseq[((size_t)t * B_ + b) * H_ + tid];
        __syncthreads();
        float partial = 0.f;
#pragma unroll
        for (int i = 0; i < 32; i++) partial = fmaf(wreg[i], hl[p + 16 * i], partial);
        partial += __shfl_xor(partial, 1, 16);
        partial += __shfl_xor(partial, 2, 16);
        partial += __shfl_xor(partial, 4, 16);
        partial += __shfl_xor(partial, 8, 16);
        acc = fmaf(decay[t], sigmoidf_(partial + bsc), acc);
    }
    if (p == 0) {
        // spreads = DECAY^T (==0 in fp32) + 0.15 * acc
        flatT[(c * 514 + 512) * B_ + b] = 0.15f * acc;
    }
}

// ---------- weights -> softmax -> nw rows of flatT ----------
__global__ __launch_bounds__(1024) void k_weights(const float* __restrict__ hsumT,
                                                  const float* __restrict__ ww,
                                                  const float* __restrict__ bw,
                                                  float* __restrict__ flatT) {
    int tid = threadIdx.x;
    __shared__ float wmat[C_ * B_];
    __shared__ float mb[B_], sb[B_];
    int b = tid & 63;
    int c0 = tid >> 6;  // 0..15
    float a0 = 0.f, a1 = 0.f;
    for (int h = 0; h < H_; h++) {
        float hv = hsumT[h * B_ + b];
        a0 = fmaf(ww[c0 * H_ + h], hv, a0);
        a1 = fmaf(ww[(c0 + 16) * H_ + h], hv, a1);
    }
    wmat[c0 * B_ + b] = a0 + 1024.0f * bw[c0];
    wmat[(c0 + 16) * B_ + b] = a1 + 1024.0f * bw[c0 + 16];
    __syncthreads();
    if (tid < 64) {
        float m = -1e30f;
        for (int c = 0; c < C_; c++) m = fmaxf(m, wmat[c * B_ + tid]);
        float s = 0.f;
        for (int c = 0; c < C_; c++) s += __expf(wmat[c * B_ + tid] - m);
        mb[tid] = m;
        sb[tid] = 1.0f / s;
    }
    __syncthreads();
    float nw0 = __expf(wmat[c0 * B_ + b] - mb[b]) * sb[b];
    float nw1 = __expf(wmat[(c0 + 16) * B_ + b] - mb[b]) * sb[b];
    flatT[(c0 * 514 + 513) * B_ + b] = nw0;
    flatT[((c0 + 16) * 514 + 513) * B_ + b] = nw1;
}

// ---------- centers rows of flatT ----------
__global__ __launch_bounds__(64) void k_centersT(const float* __restrict__ hwT,
                                                 const float* __restrict__ wc,
                                                 const float* __restrict__ bc,
                                                 float* __restrict__ flatT) {
    int b = threadIdx.x;
    int k0 = blockIdx.x * 8;
    float acc[8] = {0, 0, 0, 0, 0, 0, 0, 0};
    for (int h = 0; h < H_; h++) {
        float hv = hwT[h * B_ + b];
#pragma unroll
        for (int r = 0; r < 8; r++) acc[r] = fmaf(wc[(size_t)(k0 + r) * H_ + h], hv, acc[r]);
    }
#pragma unroll
    for (int r = 0; r < 8; r++) {
        int k = k0 + r;
        int c = k >> 9, i = k & 511;
        flatT[(c * 514 + i) * B_ + b] = 0.15f * (acc[r] + (1.0f / 0.15f) * bc[k]);
    }
}

// ---------- classifier ----------
__global__ __launch_bounds__(256) void k_cls(const float* __restrict__ flatT,
                                             const float* __restrict__ wcls,
                                             const float* __restrict__ bcls,
                                             float* __restrict__ out) {
    int tid = threadIdx.x;
    int wv = tid >> 6, b = tid & 63;
    int j0 = blockIdx.x * 8;
    __shared__ float red[4][8][64];
    float acc[8] = {0, 0, 0, 0, 0, 0, 0, 0};
    for (int i = 0; i < 4112; i++) {
        int k = wv * 4112 + i;
        float fv = flatT[k * B_ + b];
#pragma unroll
        for (int r = 0; r < 8; r++) acc[r] = fmaf(wcls[(size_t)(j0 + r) * KCLS_ + k], fv, acc[r]);
    }
#pragma unroll
    for (int r = 0; r < 8; r++) red[wv][r][b] = acc[r];
    __syncthreads();
    for (int rr = tid; rr < 512; rr += 256) {
        int r = rr >> 6, bb = rr & 63;
        float s = red[0][r][bb] + red[1][r][bb] + red[2][r][bb] + red[3][r][bb];
        out[bb * NCLS_ + j0 + r] = s + bcls[j0 + r];
    }
}

extern "C" void kernel_launch(void* const* d_in, const int* in_sizes, int n_in,
                              void* d_out, int out_size, void* d_ws, size_t ws_size,
                              hipStream_t stream) {
    const int*   tokens = (const int*)d_in[0];
    const float* emb    = (const float*)d_in[1];
    const float* w_ih   = (const float*)d_in[2];
    const float* w_hh   = (const float*)d_in[3];
    const float* b_ih   = (const float*)d_in[4];
    const float* b_hh   = (const float*)d_in[5];
    const float* wc     = (const float*)d_in[6];
    const float* bc     = (const float*)d_in[7];
    const float* ws     = (const float*)d_in[8];
    const float* bs     = (const float*)d_in[9];
    const float* ww     = (const float*)d_in[10];
    const float* bw     = (const float*)d_in[11];
    const float* wcls   = (const float*)d_in[12];
    const float* bcls   = (const float*)d_in[13];
    float* out = (float*)d_out;

    char* w = (char*)d_ws;
    // workspace layout (bytes)
    u16*      xp    = (u16*)(w + 0);                     // 65536*1536*2   = 201,326,592
    float*    hseq  = (float*)(w + 201326592);           // 1024*64*512*4  = 134,217,728
    u16*      X16   = (u16*)(w + 335544320);             // 65536*512*2    =  67,108,864
    u16*      Wih16 = (u16*)(w + 402653184);             // 1536*512*2     =   1,572,864
    unsigned* wP    = (unsigned*)(w + 404226048);        // 256*1536*4     =   1,572,864
    float*    decay = (float*)(w + 405798912);           // 1024*4
    float*    hwT   = (float*)(w + 405803008);           // 512*64*4       =     131,072
    float*    hsumT = (float*)(w + 405934080);           // 512*64*4       =     131,072
    float*    flatT = (float*)(w + 406065152);           // 16448*64*4     =   4,210,688
    // total: 410,275,840 bytes

    k_cast_wih<<<dim3((G_ * H_ + 255) / 256), dim3(256), 0, stream>>>(w_ih, Wih16);
    k_pack_whh<<<dim3((256 * G_ + 255) / 256), dim3(256), 0, stream>>>(w_hh, wP);
    k_decay<<<dim3(4), dim3(256), 0, stream>>>(decay);
    k_embed<<<dim3(16384), dim3(256), 0, stream>>>(tokens, emb, X16);
    k_xp<<<dim3(12288), dim3(256), 0, stream>>>(X16, Wih16, b_ih, xp);
    k_scan<<<dim3(64), dim3(512), 0, stream>>>(wP, xp, b_hh, hseq);
    k_hw<<<dim3(64), dim3(512), 0, stream>>>(hseq, decay, hwT, hsumT);
    k_sd<<<dim3(64), dim3(512), 0, stream>>>(hseq, ws, bs, decay, flatT);
    k_weights<<<dim3(1), dim3(1024), 0, stream>>>(hsumT, ww, bw, flatT);
    k_centersT<<<dim3(2048), dim3(64), 0, stream>>>(hwT, wc, bc, flatT);
    k_cls<<<dim3(125), dim3(256), 0, stream>>>(flatT, wcls, bcls, out);
}